// Round 8
// baseline (114.875 us; speedup 1.0000x reference)
//
#include <hip/hip_runtime.h>
#include <hip/hip_bf16.h>
#include <stdint.h>

// Problem constants
#define NROWS 8192
#define FDIM 256
#define MCOLS 20000
#define NT32 625           // 20000 / 32, exact -> no tail masking
#define MSPLIT 16
#define NCLS 1000
#define LOG2E 1.44269504088896f
#define LN2   0.69314718055994f

// ws layout (bytes), total ~15.5 MB:
//   Mb   bf16 memory          : [0, 10240000)
//   Fb   bf16 box*5*log2e     : [10240000, 14434304)
//   wsel weighted sel logits  : [14434304, 14467072)
//   pm   partial max [16][N]  : [14467072, 14991360)
//   ps   partial sum [16][N]  : [14991360, 15515648)
//   bpart block partials      : [15515648, 15515776)

typedef short short8 __attribute__((ext_vector_type(8)));
typedef float f32x4 __attribute__((ext_vector_type(4)));

typedef __attribute__((address_space(3))) unsigned int lds_u32;
typedef const __attribute__((address_space(1))) unsigned int glb_u32;

__device__ __forceinline__ float ex2(float x) {   // raw v_exp_f32 (2^x), no ocml wrapper
    float r;
    asm("v_exp_f32 %0, %1" : "=v"(r) : "v"(x));
    return r;
}

__device__ __forceinline__ f32x4 mfma16(short8 a, short8 b, f32x4 c) {
    return __builtin_amdgcn_mfma_f32_16x16x32_bf16(a, b, c, 0, 0, 0);
}

__device__ __forceinline__ unsigned short f2bf(float x) {
    unsigned u = __float_as_uint(x);
    unsigned r = (u + 0x7FFFu + ((u >> 16) & 1u)) >> 16;   // RNE
    return (unsigned short)r;
}

__global__ void conv_kernel(const float* __restrict__ in, unsigned short* __restrict__ out,
                            int n4, float scale) {
    int idx = blockIdx.x * blockDim.x + threadIdx.x;
    if (idx >= n4) return;
    float4 v = ((const float4*)in)[idx];
    ushort4 o;
    o.x = f2bf(v.x * scale); o.y = f2bf(v.y * scale);
    o.z = f2bf(v.z * scale); o.w = f2bf(v.w * scale);
    ((ushort4*)out)[idx] = o;
}

// Selected logits: wsel[i] = 5 * sum_d d * dot(F[i], Mem[trace[label_i][d]]), fp32-exact,
// natural-log domain (independent of the exp2 trick in lse_gemm).
__global__ void sel_kernel(const int* __restrict__ gt, const float* __restrict__ F,
                           const float* __restrict__ Mem, const int* __restrict__ trace,
                           float* __restrict__ wsel) {
    int lane = threadIdx.x & 63, wid = threadIdx.x >> 6;
    int i = blockIdx.x * 4 + wid;
    int label = gt[i];
    float w = 0.0f;
    if (label >= 0 && label < NCLS) {
        float4 fv = ((const float4*)(F + (size_t)i * FDIM))[lane];
        #pragma unroll
        for (int d = 1; d <= 3; ++d) {
            int tr = trace[label * 4 + d];
            float4 mv = ((const float4*)(Mem + (size_t)tr * FDIM))[lane];
            float dot = fv.x*mv.x + fv.y*mv.y + fv.z*mv.z + fv.w*mv.w;
            #pragma unroll
            for (int off = 32; off >= 1; off >>= 1) dot += __shfl_xor(dot, off, 64);
            w += (float)d * dot;
        }
    }
    if (lane == 0) wsel[i] = w * 5.0f;   // 1/T
}

// Fused GEMM + online log2-sum-exp2 partials.
// R3's proven-clean register/block shape (256 thr, launch_bounds(256,2), rf=2,
// dbuf 32 KiB LDS, __syncthreads). NEW: double-buffered ACCUMULATORS (named
// cA*/cB*, static indexing) -- softmax of tile t-1 issues under the MFMA of
// tile t, removing the serial MFMA->softmax tail from every tile period.
__global__ __launch_bounds__(256, 2) void lse_gemm(
        const unsigned short* __restrict__ Fb, const unsigned short* __restrict__ Mb,
        float* __restrict__ pm, float* __restrict__ ps) {
    __shared__ __align__(16) char smem[2 * 16384];  // 32 KiB, double-buffer

    const int split  = blockIdx.x;   // 0..15 ; consecutive x -> different XCDs
    const int rowblk = blockIdx.y;   // 0..63
    const int tid  = threadIdx.x;
    const int lane = tid & 63, wid = tid >> 6;
    const int r0 = lane & 15, hi = lane >> 4;
    const int rowbase = rowblk * 128 + wid * 32;

    // A fragments: lane holds row (rowbase + rf*16 + r0), k = kk*32 + hi*8 .. +8
    short8 a[2][8];
    #pragma unroll
    for (int rf = 0; rf < 2; ++rf)
        #pragma unroll
        for (int kk = 0; kk < 8; ++kk)
            a[rf][kk] = *(const short8*)(Fb + (size_t)(rowbase + rf*16 + r0) * FDIM + kk*32 + hi*8);

    float m[8], s[8];
    #pragma unroll
    for (int q = 0; q < 8; ++q) { m[q] = -3.0e38f; s[q] = 0.0f; }

    const int t0 = (split * NT32) / MSPLIT;
    const int t1 = ((split + 1) * NT32) / MSPLIT;   // 39-40 tiles per split

    // Staging: tile = 1024 granules of 16B (32 rows x 512B); 256 threads x 4 calls.
    // LDS dest LINEAR; global source pre-swizzled (o ^ (j&7)) so the read-side
    // XOR hits linear data.
    int srcoff[4];
    #pragma unroll
    for (int c = 0; c < 4; ++c) {
        const int g = (wid * 4 + c) * 64 + lane;
        const int j = g >> 5, o = g & 31;
        srcoff[c] = j * 512 + ((o ^ (j & 7)) << 4);
    }

#define STAGE(BUF, t)                                                              \
    do {                                                                           \
        const char* srcT = (const char*)Mb + (size_t)(t) * 16384;                  \
        _Pragma("unroll")                                                          \
        for (int c = 0; c < 4; ++c) {                                              \
            __builtin_amdgcn_global_load_lds(                                      \
                (glb_u32*)(srcT + srcoff[c]),                                      \
                (lds_u32*)(smem + (BUF) * 16384 + (wid * 4 + c) * 1024),           \
                16, 0, 0);                                                         \
        }                                                                          \
    } while (0)

    // Hoisted swizzled read offsets (per kk); buf/col-half fold into imm offsets.
    const int swzr = (r0 & 7) << 4;
    int roff[8];
    #pragma unroll
    for (int kk = 0; kk < 8; ++kk)
        roff[kk] = r0 * 512 + ((kk * 64 + hi * 16) ^ swzr);

    // Double-buffered accumulators (named, static indexing -- rule #20).
    f32x4 cA00, cA01, cA10, cA11, cB00, cB01, cB10, cB11;

#define MFMA_TILE(BUF, S)                                                          \
    do {                                                                           \
        f32x4 z = {0, 0, 0, 0};                                                    \
        c##S##00 = z; c##S##01 = z; c##S##10 = z; c##S##11 = z;                    \
        __builtin_amdgcn_s_setprio(1);                                             \
        _Pragma("unroll")                                                          \
        for (int kk = 0; kk < 8; ++kk) {                                           \
            const char* bp = smem + (BUF) * 16384 + roff[kk];                      \
            short8 b0 = *(const short8*)bp;                                        \
            short8 b1 = *(const short8*)(bp + 8192);                               \
            c##S##00 = mfma16(a[0][kk], b0, c##S##00);                             \
            c##S##10 = mfma16(a[1][kk], b0, c##S##10);                             \
            c##S##01 = mfma16(a[0][kk], b1, c##S##01);                             \
            c##S##11 = mfma16(a[1][kk], b1, c##S##11);                             \
        }                                                                          \
        __builtin_amdgcn_s_setprio(0);                                             \
    } while (0)

#define SOFTMAX(S)                                                                 \
    do {                                                                           \
        _Pragma("unroll")                                                          \
        for (int r = 0; r < 4; ++r) {                                              \
            { float v0 = c##S##00[r], v1 = c##S##01[r];                            \
              float nm = fmaxf(fmaxf(m[r], v0), v1);                               \
              float em = ex2(m[r] - nm), e0 = ex2(v0 - nm), e1 = ex2(v1 - nm);     \
              s[r] = fmaf(s[r], em, e0 + e1); m[r] = nm; }                         \
            { float v0 = c##S##10[r], v1 = c##S##11[r];                            \
              float nm = fmaxf(fmaxf(m[4 + r], v0), v1);                           \
              float em = ex2(m[4 + r] - nm), e0 = ex2(v0 - nm), e1 = ex2(v1 - nm); \
              s[4 + r] = fmaf(s[4 + r], em, e0 + e1); m[4 + r] = nm; }             \
        }                                                                          \
    } while (0)

    // Prologue: tile t0 -> accA (no previous softmax).
    STAGE(0, t0);
    __syncthreads();
    STAGE(1, t0 + 1);          // >= 39 tiles/split, always exists
    MFMA_TILE(0, A);
    __syncthreads();

    // Steady state: softmax(prev tile) overlaps MFMA(current tile).
    int t = t0 + 1;            // (t - t0) odd -> buf1/accB first
    while (t + 2 <= t1) {
        STAGE(0, t + 1);
        MFMA_TILE(1, B);
        SOFTMAX(A);
        __syncthreads();
        if (t + 2 < t1) STAGE(1, t + 2);
        MFMA_TILE(0, A);
        SOFTMAX(B);
        __syncthreads();
        t += 2;
    }
    if (t < t1) {              // one tile left, odd offset -> buf1 (staged last iter)
        MFMA_TILE(1, B);
        SOFTMAX(A);
        SOFTMAX(B);
    } else {                   // accA holds the final tile's logits
        SOFTMAX(A);
    }

#undef SOFTMAX
#undef MFMA_TILE
#undef STAGE

    // combine the 16 lanes (r0 = column residue classes) of each hi-group
    #pragma unroll
    for (int off = 1; off <= 8; off <<= 1) {
        #pragma unroll
        for (int q = 0; q < 8; ++q) {
            float om = __shfl_xor(m[q], off, 64);
            float os = __shfl_xor(s[q], off, 64);
            float nm = fmaxf(m[q], om);
            float sn = fmaf(s[q], ex2(m[q] - nm), os * ex2(om - nm));
            m[q] = nm; s[q] = sn;
        }
    }
    if (r0 == 0) {
        #pragma unroll
        for (int rf = 0; rf < 2; ++rf)
            #pragma unroll
            for (int r = 0; r < 4; ++r) {
                int row = rowbase + rf * 16 + hi * 4 + r;   // C/D: row=(lane>>4)*4+reg
                pm[split * NROWS + row] = m[rf * 4 + r];
                ps[split * NROWS + row] = s[rf * 4 + r];
            }
    }
}

__global__ void finalize_kernel(const int* __restrict__ gt, const float* __restrict__ wsel,
                                const float* __restrict__ pm, const float* __restrict__ ps,
                                float* __restrict__ bpart) {
    int tid = threadIdx.x;
    int i = blockIdx.x * 256 + tid;
    float mv[MSPLIT];
    float M = -3.0e38f;
    #pragma unroll
    for (int k = 0; k < MSPLIT; ++k) { mv[k] = pm[k * NROWS + i]; M = fmaxf(M, mv[k]); }
    float S = 0.0f;
    #pragma unroll
    for (int k = 0; k < MSPLIT; ++k) S += ps[k * NROWS + i] * ex2(mv[k] - M);
    float lse = (M + __log2f(S)) * LN2;   // back to natural-log domain
    int label = gt[i];
    float per = (label >= 0 && label < NCLS) ? (lse - wsel[i] * (1.0f / 6.0f)) : 0.0f;
    #pragma unroll
    for (int off = 32; off >= 1; off >>= 1) per += __shfl_xor(per, off, 64);
    __shared__ float red[4];
    int lane = tid & 63, wid = tid >> 6;
    if (lane == 0) red[wid] = per;
    __syncthreads();
    if (tid == 0) bpart[blockIdx.x] = red[0] + red[1] + red[2] + red[3];
}

__global__ void sum_kernel(const float* __restrict__ bpart, float* __restrict__ out) {
    int tid = threadIdx.x;
    float v = (tid < 32) ? bpart[tid] : 0.0f;
    #pragma unroll
    for (int off = 32; off >= 1; off >>= 1) v += __shfl_xor(v, off, 64);
    if (tid == 0) out[0] = 0.001f * v;
}

extern "C" void kernel_launch(void* const* d_in, const int* in_sizes, int n_in,
                              void* d_out, int out_size, void* d_ws, size_t ws_size,
                              hipStream_t stream) {
    const int*   gt    = (const int*)d_in[0];
    const float* F     = (const float*)d_in[1];
    const float* Mem   = (const float*)d_in[2];
    const int*   trace = (const int*)d_in[3];
    float* out = (float*)d_out;

    char* w = (char*)d_ws;
    unsigned short* Mb = (unsigned short*)w;
    unsigned short* Fb = (unsigned short*)(w + 10240000);
    float* wsel  = (float*)(w + 14434304);
    float* pm    = (float*)(w + 14467072);
    float* ps    = (float*)(w + 14991360);
    float* bpart = (float*)(w + 15515648);

    conv_kernel<<<dim3((MCOLS * FDIM / 4) / 256), dim3(256), 0, stream>>>(Mem, Mb, MCOLS * FDIM / 4, 1.0f);
    conv_kernel<<<dim3((NROWS * FDIM / 4) / 256), dim3(256), 0, stream>>>(F, Fb, NROWS * FDIM / 4, 5.0f * LOG2E);
    sel_kernel<<<dim3(NROWS / 4), dim3(256), 0, stream>>>(gt, F, Mem, trace, wsel);
    lse_gemm<<<dim3(MSPLIT, NROWS / 128), dim3(256), 0, stream>>>(Fb, Mb, pm, ps);
    finalize_kernel<<<dim3(NROWS / 256), dim3(256), 0, stream>>>(gt, wsel, pm, ps, bpart);
    sum_kernel<<<dim3(1), dim3(64), 0, stream>>>(bpart, out);
}

// Round 9
// 109.160 us; speedup vs baseline: 1.0524x; 1.0524x over previous
//
#include <hip/hip_runtime.h>
#include <hip/hip_bf16.h>
#include <stdint.h>

// Problem constants
#define NROWS 8192
#define FDIM 256
#define MCOLS 20000
#define NT32 625           // 20000 / 32, exact -> no tail masking
#define MSPLIT 16
#define NCLS 1000
#define LOG2E 1.44269504088896f
#define LN2   0.69314718055994f

// ws layout (bytes), total ~15.5 MB:
//   Mb   bf16 memory          : [0, 10240000)
//   Fb   bf16 box*5*log2e     : [10240000, 14434304)
//   wsel weighted sel logits  : [14434304, 14467072)
//   pm   partial max [16][N]  : [14467072, 14991360)
//   ps   partial sum [16][N]  : [14991360, 15515648)
//   bpart block partials      : [15515648, 15515776)

typedef short short8 __attribute__((ext_vector_type(8)));
typedef float f32x16 __attribute__((ext_vector_type(16)));

typedef __attribute__((address_space(3))) unsigned int lds_u32;
typedef const __attribute__((address_space(1))) unsigned int glb_u32;

__device__ __forceinline__ float ex2(float x) {   // raw v_exp_f32 (2^x), no ocml wrapper
    float r;
    asm("v_exp_f32 %0, %1" : "=v"(r) : "v"(x));
    return r;
}

__device__ __forceinline__ unsigned short f2bf(float x) {
    unsigned u = __float_as_uint(x);
    unsigned r = (u + 0x7FFFu + ((u >> 16) & 1u)) >> 16;   // RNE
    return (unsigned short)r;
}

__global__ void conv_kernel(const float* __restrict__ in, unsigned short* __restrict__ out,
                            int n4, float scale) {
    int idx = blockIdx.x * blockDim.x + threadIdx.x;
    if (idx >= n4) return;
    float4 v = ((const float4*)in)[idx];
    ushort4 o;
    o.x = f2bf(v.x * scale); o.y = f2bf(v.y * scale);
    o.z = f2bf(v.z * scale); o.w = f2bf(v.w * scale);
    ((ushort4*)out)[idx] = o;
}

// Selected logits: wsel[i] = 5 * sum_d d * dot(F[i], Mem[trace[label_i][d]]), fp32-exact,
// natural-log domain (independent of the exp2 trick in lse_gemm).
__global__ void sel_kernel(const int* __restrict__ gt, const float* __restrict__ F,
                           const float* __restrict__ Mem, const int* __restrict__ trace,
                           float* __restrict__ wsel) {
    int lane = threadIdx.x & 63, wid = threadIdx.x >> 6;
    int i = blockIdx.x * 4 + wid;
    int label = gt[i];
    float w = 0.0f;
    if (label >= 0 && label < NCLS) {
        float4 fv = ((const float4*)(F + (size_t)i * FDIM))[lane];
        #pragma unroll
        for (int d = 1; d <= 3; ++d) {
            int tr = trace[label * 4 + d];
            float4 mv = ((const float4*)(Mem + (size_t)tr * FDIM))[lane];
            float dot = fv.x*mv.x + fv.y*mv.y + fv.z*mv.z + fv.w*mv.w;
            #pragma unroll
            for (int off = 32; off >= 1; off >>= 1) dot += __shfl_xor(dot, off, 64);
            w += (float)d * dot;
        }
    }
    if (lane == 0) wsel[i] = w * 5.0f;   // 1/T
}

// Fused GEMM + online log2-sum-exp2 partials -- SWAPPED-OPERAND 32x32x16.
// mfma(B_frag, A_frag): output col=lane&31 -> A-row, row-index -> B-col, so each
// lane holds 16 cols of ONE row -> softmax batches 16 values per exp-rescale
// (17 ex2 / 16 values vs 3/2 before) and m,s shrink to scalars.
// Per wave: 32 rows (a[16] = 64 VGPR), 32-col B tile, 16 MFMA + 16 ds_read_b128.
// B tile (32 rows x 512B) in LDS, 5-bit XOR granule swizzle (full bank spread);
// LDS dest linear, global source pre-swizzled. R3's proven 1-barrier dbuf loop.
__global__ __launch_bounds__(256, 2) void lse_gemm(
        const unsigned short* __restrict__ Fb, const unsigned short* __restrict__ Mb,
        float* __restrict__ pm, float* __restrict__ ps) {
    __shared__ __align__(16) char smem[2 * 16384];  // 32 KiB, double-buffer

    const int split  = blockIdx.x;   // 0..15 ; consecutive x -> different XCDs
    const int rowblk = blockIdx.y;   // 0..63
    const int tid  = threadIdx.x;
    const int lane = tid & 63, wid = tid >> 6;
    const int r0 = lane & 31;        // A-row within wave AND B-col for the X-operand
    const int hi = lane >> 5;        // k-slice half
    const int rowbase = rowblk * 128 + wid * 32;

    // A fragments (Y-operand): lane holds row (rowbase + r0), k = kk*16 + hi*8 .. +8
    short8 a[16];
    #pragma unroll
    for (int kk = 0; kk < 16; ++kk)
        a[kk] = *(const short8*)(Fb + (size_t)(rowbase + r0) * FDIM + kk * 16 + hi * 8);

    float m = -3.0e38f, s = 0.0f;    // scalar online state: one row per lane

    const int t0 = (split * NT32) / MSPLIT;
    const int t1 = ((split + 1) * NT32) / MSPLIT;   // 39-40 tiles per split

    // Staging: tile = 1024 granules of 16B (32 rows x 512B); 256 threads x 4 calls.
    // LDS dest LINEAR; global source pre-swizzled with FULL 5-bit XOR (o ^ j) so
    // the read-side XOR lands on linear data and 32 rows spread over 32 granules.
    int srcoff[4];
    #pragma unroll
    for (int c = 0; c < 4; ++c) {
        const int g = (wid * 4 + c) * 64 + lane;
        const int j = g >> 5, o = g & 31;
        srcoff[c] = j * 512 + ((o ^ j) << 4);
    }

#define STAGE(BUF, t)                                                              \
    do {                                                                           \
        const char* srcT = (const char*)Mb + (size_t)(t) * 16384;                  \
        _Pragma("unroll")                                                          \
        for (int c = 0; c < 4; ++c) {                                              \
            __builtin_amdgcn_global_load_lds(                                      \
                (glb_u32*)(srcT + srcoff[c]),                                      \
                (lds_u32*)(smem + (BUF) * 16384 + (wid * 4 + c) * 1024),           \
                16, 0, 0);                                                         \
        }                                                                          \
    } while (0)

    // Read offsets: X-operand (B) frag for kk: row r0, granule g=2kk+hi, swizzled
    // granule g^r0. 16 precomputed byte offsets.
    int roff[16];
    #pragma unroll
    for (int kk = 0; kk < 16; ++kk)
        roff[kk] = r0 * 512 + ((((kk << 1) | hi) ^ r0) << 4);

#define BODYC(BUF)                                                                 \
    do {                                                                           \
        f32x16 acc = {0,0,0,0,0,0,0,0,0,0,0,0,0,0,0,0};                            \
        __builtin_amdgcn_s_setprio(1);                                             \
        _Pragma("unroll")                                                          \
        for (int kk = 0; kk < 16; ++kk) {                                          \
            short8 b = *(const short8*)(smem + (BUF) * 16384 + roff[kk]);          \
            acc = __builtin_amdgcn_mfma_f32_32x32x16_bf16(b, a[kk], acc, 0, 0, 0); \
        }                                                                          \
        __builtin_amdgcn_s_setprio(0);                                             \
        float x0 = fmaxf(fmaxf(acc[0],  acc[1]),  acc[2]);                         \
        float x1 = fmaxf(fmaxf(acc[3],  acc[4]),  acc[5]);                         \
        float x2 = fmaxf(fmaxf(acc[6],  acc[7]),  acc[8]);                         \
        float x3 = fmaxf(fmaxf(acc[9],  acc[10]), acc[11]);                        \
        float x4 = fmaxf(fmaxf(acc[12], acc[13]), acc[14]);                        \
        float x5 = fmaxf(fmaxf(x0, x1), x2);                                       \
        float x6 = fmaxf(fmaxf(x3, x4), acc[15]);                                  \
        float nm = fmaxf(fmaxf(x5, x6), m);                                        \
        float p0 = 0.f, p1 = 0.f, p2 = 0.f, p3 = 0.f;                              \
        _Pragma("unroll")                                                          \
        for (int i = 0; i < 16; i += 4) {                                          \
            p0 += ex2(acc[i]     - nm); p1 += ex2(acc[i + 1] - nm);                \
            p2 += ex2(acc[i + 2] - nm); p3 += ex2(acc[i + 3] - nm);                \
        }                                                                          \
        s = fmaf(s, ex2(m - nm), (p0 + p1) + (p2 + p3));                           \
        m = nm;                                                                    \
    } while (0)

    STAGE(0, t0);
    __syncthreads();

    int t = t0;
    while (t + 2 <= t1) {
        STAGE(1, t + 1);               // t+1 < t1 inside this loop
        BODYC(0);
        __syncthreads();
        if (t + 2 < t1) STAGE(0, t + 2);
        BODYC(1);
        __syncthreads();
        t += 2;
    }
    if (t < t1) BODYC(0);              // staged by the last iteration

#undef BODYC
#undef STAGE

    // Combine the two k-slice halves: lane l and l^32 hold the same row's two
    // 16-col subsets.
    {
        float om = __shfl_xor(m, 32, 64);
        float os = __shfl_xor(s, 32, 64);
        float nm = fmaxf(m, om);
        float sf = fmaf(s, ex2(m - nm), os * ex2(om - nm));
        if (lane < 32) {
            pm[split * NROWS + rowbase + lane] = nm;
            ps[split * NROWS + rowbase + lane] = sf;
        }
    }
}

__global__ void finalize_kernel(const int* __restrict__ gt, const float* __restrict__ wsel,
                                const float* __restrict__ pm, const float* __restrict__ ps,
                                float* __restrict__ bpart) {
    int tid = threadIdx.x;
    int i = blockIdx.x * 256 + tid;
    float mv[MSPLIT];
    float M = -3.0e38f;
    #pragma unroll
    for (int k = 0; k < MSPLIT; ++k) { mv[k] = pm[k * NROWS + i]; M = fmaxf(M, mv[k]); }
    float S = 0.0f;
    #pragma unroll
    for (int k = 0; k < MSPLIT; ++k) S += ps[k * NROWS + i] * ex2(mv[k] - M);
    float lse = (M + __log2f(S)) * LN2;   // back to natural-log domain
    int label = gt[i];
    float per = (label >= 0 && label < NCLS) ? (lse - wsel[i] * (1.0f / 6.0f)) : 0.0f;
    #pragma unroll
    for (int off = 32; off >= 1; off >>= 1) per += __shfl_xor(per, off, 64);
    __shared__ float red[4];
    int lane = tid & 63, wid = tid >> 6;
    if (lane == 0) red[wid] = per;
    __syncthreads();
    if (tid == 0) bpart[blockIdx.x] = red[0] + red[1] + red[2] + red[3];
}

__global__ void sum_kernel(const float* __restrict__ bpart, float* __restrict__ out) {
    int tid = threadIdx.x;
    float v = (tid < 32) ? bpart[tid] : 0.0f;
    #pragma unroll
    for (int off = 32; off >= 1; off >>= 1) v += __shfl_xor(v, off, 64);
    if (tid == 0) out[0] = 0.001f * v;
}

extern "C" void kernel_launch(void* const* d_in, const int* in_sizes, int n_in,
                              void* d_out, int out_size, void* d_ws, size_t ws_size,
                              hipStream_t stream) {
    const int*   gt    = (const int*)d_in[0];
    const float* F     = (const float*)d_in[1];
    const float* Mem   = (const float*)d_in[2];
    const int*   trace = (const int*)d_in[3];
    float* out = (float*)d_out;

    char* w = (char*)d_ws;
    unsigned short* Mb = (unsigned short*)w;
    unsigned short* Fb = (unsigned short*)(w + 10240000);
    float* wsel  = (float*)(w + 14434304);
    float* pm    = (float*)(w + 14467072);
    float* ps    = (float*)(w + 14991360);
    float* bpart = (float*)(w + 15515648);

    conv_kernel<<<dim3((MCOLS * FDIM / 4) / 256), dim3(256), 0, stream>>>(Mem, Mb, MCOLS * FDIM / 4, 1.0f);
    conv_kernel<<<dim3((NROWS * FDIM / 4) / 256), dim3(256), 0, stream>>>(F, Fb, NROWS * FDIM / 4, 5.0f * LOG2E);
    sel_kernel<<<dim3(NROWS / 4), dim3(256), 0, stream>>>(gt, F, Mem, trace, wsel);
    lse_gemm<<<dim3(MSPLIT, NROWS / 128), dim3(256), 0, stream>>>(Fb, Mb, pm, ps);
    finalize_kernel<<<dim3(NROWS / 256), dim3(256), 0, stream>>>(gt, wsel, pm, ps, bpart);
    sum_kernel<<<dim3(1), dim3(64), 0, stream>>>(bpart, out);
}